// Round 3
// baseline (156.733 us; speedup 1.0000x reference)
//
#include <hip/hip_runtime.h>

typedef __attribute__((ext_vector_type(8))) short short8;
typedef __attribute__((ext_vector_type(4))) short short4v;
typedef __attribute__((ext_vector_type(4))) float f32x4;

#define LN1000_OVER_512 0.0134917095f

// ws layout (f32 offsets)
#define IMGB_OFF  0        // bf16 [112][256]  rows 0..63 = x/h, 64..111 = y/w
#define PARTV_OFF 14336    // f32 [4][32][512] K-split partials of v
#define BVB_OFF   79872    // bf16 [32][12544] == [n][k*256+o]
#define APPT_OFF  280576   // f32 [4][3072][52] (k padded 49->52)

__device__ __forceinline__ short f2bf(float x) {
  unsigned u = __float_as_uint(x);
  return (short)((u + 0x7FFFu + ((u >> 16) & 1u)) >> 16);
}
__device__ __forceinline__ short4v f2bf4(float4 v) {
  short4v r; r.x = f2bf(v.x); r.y = f2bf(v.y); r.z = f2bf(v.z); r.w = f2bf(v.w);
  return r;
}

// K1: three independent GEMM families in one launch.
//  bid 0..63    v-partials: v[32][512] = eps(32x2048).V_box^T, K-split x4 (ks == roi coord!)
//  bid 64..95   img GEMM:   imgb[112][256] = embed(pos).W_im_half^T
//  bid 96..479  app GEMM:   appT[b][p][k] = x[b][:][p]^T.conv_w^T + conv_b
__global__ __launch_bounds__(256) void k1(const float* __restrict__ rois,
                                          const float* __restrict__ W_im,
                                          const float* __restrict__ V_box,
                                          const float* __restrict__ x,
                                          const float* __restrict__ conv_w,
                                          const float* __restrict__ conv_b,
                                          float* __restrict__ ws) {
  __shared__ __align__(16) short sh[96 * 264];
  int bid = blockIdx.x, tid = threadIdx.x;
  int w = tid >> 6, lane = tid & 63;
  int q = lane >> 4, m = lane & 15;

  if (bid < 96) {
    short* Al = sh;              // [32][264]
    short* Bl = sh + 32 * 264;   // [32][264]
    float inv_s = __expf(-LN1000_OVER_512 * (float)(2 * tid + 1));
    float inv_c = __expf(-LN1000_OVER_512 * (float)(2 * tid));
    f32x4 acc = {0.f, 0.f, 0.f, 0.f};
    int m0 = (w & 1) * 16, n0 = (w >> 1) * 16;

    if (bid < 64) {
      // ---- v partial: ks selects both K-window and roi coordinate
      int ntb = bid & 15, ks = bid >> 4;
      int d0 = ntb * 32;
      for (int c = 0; c < 2; ++c) {
        int k0 = ks * 512 + c * 256;
        for (int j = 0; j < 32; ++j) {
          float z = rois[j * 5 + 1 + ks];
          float val = c ? __cosf(z * inv_c) : __sinf(z * inv_s);
          Al[j * 264 + tid] = f2bf(val);
        }
        #pragma unroll
        for (int jj = 0; jj < 8; ++jj) {
          int fid = tid + jj * 256;
          int dd = fid >> 6, k4 = fid & 63;
          float4 v = *(const float4*)(V_box + (size_t)(d0 + dd) * 2048 + k0 + k4 * 4);
          *(short4v*)(Bl + dd * 264 + k4 * 4) = f2bf4(v);
        }
        __syncthreads();
        const short* ap = Al + (m0 + m) * 264 + q * 8;
        const short* bp = Bl + (n0 + m) * 264 + q * 8;
        #pragma unroll
        for (int kk = 0; kk < 8; ++kk) {
          short8 a = *(const short8*)(ap + kk * 32);
          short8 b = *(const short8*)(bp + kk * 32);
          acc = __builtin_amdgcn_mfma_f32_16x16x32_bf16(a, b, acc, 0, 0, 0);
        }
        __syncthreads();
      }
      #pragma unroll
      for (int r = 0; r < 4; ++r)
        ws[PARTV_OFF + ks * 16384 + (m0 + q * 4 + r) * 512 + d0 + n0 + m] = acc[r];
    } else {
      // ---- img GEMM: rows 0..111 (pad to 128), cols 256
      int t = bid - 64;
      int mt = t >> 3, nt = t & 7;
      int rm0 = mt * 32, o0 = nt * 32;
      int khalf = mt >> 1;                 // 0: x-half, 1: y-half of W_im cols
      int posbase = rm0 - khalf * 64;
      for (int c = 0; c < 2; ++c) {
        int k0 = khalf * 512 + c * 256;
        for (int j = 0; j < 32; ++j) {
          float z = (float)(posbase + j);
          float val = c ? __cosf(z * inv_c) : __sinf(z * inv_s);
          Al[j * 264 + tid] = f2bf(val);
        }
        #pragma unroll
        for (int jj = 0; jj < 8; ++jj) {
          int fid = tid + jj * 256;
          int dd = fid >> 6, k4 = fid & 63;
          float4 v = *(const float4*)(W_im + (size_t)(o0 + dd) * 1024 + k0 + k4 * 4);
          *(short4v*)(Bl + dd * 264 + k4 * 4) = f2bf4(v);
        }
        __syncthreads();
        const short* ap = Al + (m0 + m) * 264 + q * 8;
        const short* bp = Bl + (n0 + m) * 264 + q * 8;
        #pragma unroll
        for (int kk = 0; kk < 8; ++kk) {
          short8 a = *(const short8*)(ap + kk * 32);
          short8 b = *(const short8*)(bp + kk * 32);
          acc = __builtin_amdgcn_mfma_f32_16x16x32_bf16(a, b, acc, 0, 0, 0);
        }
        __syncthreads();
      }
      short* imgb = (short*)(ws + IMGB_OFF);
      #pragma unroll
      for (int r = 0; r < 4; ++r) {
        int row = rm0 + m0 + q * 4 + r;
        if (row < 112) imgb[row * 256 + o0 + n0 + m] = f2bf(acc[r]);
      }
    }
  } else {
    // ---- app GEMM
    short* Al = sh;                  // [32 px][264 c]
    short* Bl = sh + 32 * 264;       // [64 k][264 c]
    int t = bid - 96;
    int b = t / 96, pt = t % 96;
    int p0 = pt * 32;
    const float* xb = x + (size_t)b * 786432;
    #pragma unroll
    for (int j = 0; j < 8; ++j) {
      int fid = tid + j * 256;
      int c = fid >> 3, pj = fid & 7;
      float4 v = *(const float4*)(xb + c * 3072 + p0 + pj * 4);
      Al[(pj * 4 + 0) * 264 + c] = f2bf(v.x);
      Al[(pj * 4 + 1) * 264 + c] = f2bf(v.y);
      Al[(pj * 4 + 2) * 264 + c] = f2bf(v.z);
      Al[(pj * 4 + 3) * 264 + c] = f2bf(v.w);
    }
    #pragma unroll
    for (int j = 0; j < 16; ++j) {
      int fid = tid + j * 256;
      int k = fid >> 6, c4 = fid & 63;
      short4v s4 = {0, 0, 0, 0};
      if (k < 49) s4 = f2bf4(*(const float4*)(conv_w + k * 256 + c4 * 4));
      *(short4v*)(Bl + k * 264 + c4 * 4) = s4;
    }
    __syncthreads();
    int n0 = w * 16;
    f32x4 acc0 = {0.f, 0.f, 0.f, 0.f}, acc1 = {0.f, 0.f, 0.f, 0.f};
    const short* ap = Al + m * 264 + q * 8;
    const short* bp = Bl + (n0 + m) * 264 + q * 8;
    #pragma unroll
    for (int kk = 0; kk < 8; ++kk) {
      short8 b8 = *(const short8*)(bp + kk * 32);
      short8 a0 = *(const short8*)(ap + kk * 32);
      short8 a1 = *(const short8*)(ap + 16 * 264 + kk * 32);
      acc0 = __builtin_amdgcn_mfma_f32_16x16x32_bf16(a0, b8, acc0, 0, 0, 0);
      acc1 = __builtin_amdgcn_mfma_f32_16x16x32_bf16(a1, b8, acc1, 0, 0, 0);
    }
    int k = n0 + m;
    if (k < 49) {
      float bias = conv_b[k];
      float* apt = ws + APPT_OFF + (size_t)b * 159744;
      #pragma unroll
      for (int r = 0; r < 4; ++r) {
        int p = p0 + q * 4 + r;
        apt[(size_t)p * 52 + k] = acc0[r] + bias;
        apt[(size_t)(p + 16) * 52 + k] = acc1[r] + bias;
      }
    }
  }
}

// K2: bvec_bf16[n][12544] = v(32x512).W_box(12544x512)^T ; v staged by summing 4 partials
__global__ __launch_bounds__(256) void k2(const float* __restrict__ W_box,
                                          float* __restrict__ ws) {
  __shared__ __align__(16) short Av[32 * 520];
  __shared__ __align__(16) short Bl[32 * 520];
  int tid = threadIdx.x;
  int j0 = blockIdx.x * 32;   // 392 blocks
  #pragma unroll
  for (int j = 0; j < 16; ++j) {
    int fid = tid + j * 256;
    int n = fid >> 7, d4 = fid & 127;
    const float* p = ws + PARTV_OFF + n * 512 + d4 * 4;
    float4 v0 = *(const float4*)(p);
    float4 v1 = *(const float4*)(p + 16384);
    float4 v2 = *(const float4*)(p + 32768);
    float4 v3 = *(const float4*)(p + 49152);
    float4 s; s.x = v0.x + v1.x + v2.x + v3.x; s.y = v0.y + v1.y + v2.y + v3.y;
    s.z = v0.z + v1.z + v2.z + v3.z; s.w = v0.w + v1.w + v2.w + v3.w;
    *(short4v*)(Av + n * 520 + d4 * 4) = f2bf4(s);
  }
  #pragma unroll
  for (int j = 0; j < 16; ++j) {
    int fid = tid + j * 256;
    int rr = fid >> 7, d4 = fid & 127;
    float4 v = *(const float4*)(W_box + (size_t)(j0 + rr) * 512 + d4 * 4);
    *(short4v*)(Bl + rr * 520 + d4 * 4) = f2bf4(v);
  }
  __syncthreads();
  int w = tid >> 6, lane = tid & 63;
  int q = lane >> 4, m = lane & 15;
  int m0 = (w & 1) * 16, n0 = (w >> 1) * 16;
  f32x4 acc = {0.f, 0.f, 0.f, 0.f};
  const short* ap = Av + (m0 + m) * 520 + q * 8;
  const short* bp = Bl + (n0 + m) * 520 + q * 8;
  #pragma unroll
  for (int kk = 0; kk < 16; ++kk) {
    short8 a = *(const short8*)(ap + kk * 32);
    short8 b = *(const short8*)(bp + kk * 32);
    acc = __builtin_amdgcn_mfma_f32_16x16x32_bf16(a, b, acc, 0, 0, 0);
  }
  short* bvb = (short*)(ws + BVB_OFF);
  #pragma unroll
  for (int r = 0; r < 4; ++r) {
    int row = m0 + q * 4 + r;
    int col = j0 + n0 + m;
    bvb[(size_t)row * 12544 + col] = f2bf(acc[r]);
  }
}

// K3: per (n,tile): phase A computes gx(49x64)/gy(49x48) into LDS via MFMA
//     reading A/B fragments straight from L2-hot bvb/imgb; phase B = softmax+write.
__global__ __launch_bounds__(256) void k3(const float* __restrict__ rois,
                                          const float* __restrict__ ws,
                                          float* __restrict__ out) {
  __shared__ float gxl[64 * 64];
  __shared__ float gyl[64 * 48];
  __shared__ int rank_sh;
  int tid = threadIdx.x, bid = blockIdx.x;   // 384 = 32 n x 12 tiles
  int n = bid / 12, tile = bid % 12;
  int w = tid >> 6, lane = tid & 63;
  int q = lane >> 4, m = lane & 15;
  const short* bvb  = (const short*)(ws + BVB_OFF);
  const short* imgb = (const short*)(ws + IMGB_OFF);

  if (tid == 0) {
    float my = rois[n * 5];
    int r = 0;
    for (int mm = 0; mm < 32; ++mm) {
      float vm = rois[mm * 5];
      if (vm < my || (vm == my && mm < n)) ++r;
    }
    rank_sh = r;
  }

  // phase A: 28 tiles of 16x16 (gx: 4kt x 4ht, gy: 4kt x 3wt), K=256
  for (int t = w; t < 28; t += 4) {
    int kt, rB; bool isy = t >= 16;
    if (!isy) { kt = t >> 2; rB = (t & 3) * 16; }
    else { int tt = t - 16; kt = tt / 3; rB = 64 + (tt % 3) * 16; }
    f32x4 acc = {0.f, 0.f, 0.f, 0.f};
    const short* ap = bvb + ((size_t)n * 49 + kt * 16 + m) * 256 + q * 8;
    const short* bp = imgb + (rB + m) * 256 + q * 8;
    #pragma unroll
    for (int s = 0; s < 8; ++s) {
      short8 a = *(const short8*)(ap + s * 32);
      short8 b = *(const short8*)(bp + s * 32);
      acc = __builtin_amdgcn_mfma_f32_16x16x32_bf16(a, b, acc, 0, 0, 0);
    }
    #pragma unroll
    for (int r = 0; r < 4; ++r) {
      int kk = kt * 16 + q * 4 + r;
      if (!isy) gxl[kk * 64 + rB + m] = acc[r];
      else      gyl[kk * 48 + (rB - 64) + m] = acc[r];
    }
  }
  __syncthreads();

  // phase B
  int pix = tile * 256 + tid;
  int h = pix / 48, wv = pix - h * 48;
  int r = rank_sh;
  for (int b = 0; b < 4; ++b) {
    const float* ap = ws + APPT_OFF + (size_t)(b * 3072 + pix) * 52;
    float lg[49];
    #pragma unroll
    for (int qq = 0; qq < 12; ++qq) {
      float4 tv = *(const float4*)(ap + qq * 4);
      lg[qq * 4 + 0] = tv.x; lg[qq * 4 + 1] = tv.y; lg[qq * 4 + 2] = tv.z; lg[qq * 4 + 3] = tv.w;
    }
    lg[48] = ap[48];
    #pragma unroll
    for (int k = 0; k < 49; ++k)
      lg[k] += gxl[k * 64 + h] + gyl[k * 48 + wv];
    float mx = lg[0];
    #pragma unroll
    for (int k = 1; k < 49; ++k) mx = fmaxf(mx, lg[k]);
    float s = 0.f;
    #pragma unroll
    for (int k = 0; k < 49; ++k) { float e = __expf(lg[k] - mx); lg[k] = e; s += e; }
    float inv = 1.f / s;
    float* op = out + (size_t)(r * 4 + b) * 150528 + pix;
    #pragma unroll
    for (int k = 0; k < 49; ++k)
      op[(size_t)k * 3072] = lg[k] * inv;
  }
}

extern "C" void kernel_launch(void* const* d_in, const int* in_sizes, int n_in,
                              void* d_out, int out_size, void* d_ws, size_t ws_size,
                              hipStream_t stream) {
  const float* x      = (const float*)d_in[0];
  const float* rois   = (const float*)d_in[1];
  const float* V_box  = (const float*)d_in[2];
  const float* W_box  = (const float*)d_in[3];
  const float* W_im   = (const float*)d_in[4];
  const float* conv_w = (const float*)d_in[5];
  const float* conv_b = (const float*)d_in[6];
  float* ws  = (float*)d_ws;
  float* out = (float*)d_out;

  hipLaunchKernelGGL(k1, dim3(480), dim3(256), 0, stream, rois, W_im, V_box, x, conv_w, conv_b, ws);
  hipLaunchKernelGGL(k2, dim3(392), dim3(256), 0, stream, W_box, ws);
  hipLaunchKernelGGL(k3, dim3(384), dim3(256), 0, stream, rois, ws, out);
}

// Round 4
// 143.768 us; speedup vs baseline: 1.0902x; 1.0902x over previous
//
#include <hip/hip_runtime.h>

typedef __attribute__((ext_vector_type(8))) short short8;
typedef __attribute__((ext_vector_type(4))) short short4v;
typedef __attribute__((ext_vector_type(4))) float f32x4;

#define LN1000_OVER_512 0.0134917095f

// ws layout (f32 offsets)
#define IMGB_OFF  0        // bf16 [112][256]  rows 0..63 = x/h, 64..111 = y/w
#define PARTV_OFF 14336    // f32 [4][32][512] K-split partials of v
#define BVB_OFF   79872    // bf16 [32][12544] == [n][k*256+o]
#define APPT_OFF  280576   // f32 [4][3072][52] (k padded 49->52)
#define GX_OFF    919552   // f32 [1568][64]
#define GY_OFF    1019904  // f32 [1568][48]

__device__ __forceinline__ short f2bf(float x) {
  unsigned u = __float_as_uint(x);
  return (short)((u + 0x7FFFu + ((u >> 16) & 1u)) >> 16);
}
__device__ __forceinline__ short4v f2bf4(float4 v) {
  short4v r; r.x = f2bf(v.x); r.y = f2bf(v.y); r.z = f2bf(v.z); r.w = f2bf(v.w);
  return r;
}

// K1: three independent GEMM families in one launch.
__global__ __launch_bounds__(256) void k1(const float* __restrict__ rois,
                                          const float* __restrict__ W_im,
                                          const float* __restrict__ V_box,
                                          const float* __restrict__ x,
                                          const float* __restrict__ conv_w,
                                          const float* __restrict__ conv_b,
                                          float* __restrict__ ws) {
  __shared__ __align__(16) short sh[96 * 264];
  int bid = blockIdx.x, tid = threadIdx.x;
  int w = tid >> 6, lane = tid & 63;
  int q = lane >> 4, m = lane & 15;

  if (bid < 96) {
    short* Al = sh;              // [32][264]
    short* Bl = sh + 32 * 264;   // [32][264]
    float inv_s = __expf(-LN1000_OVER_512 * (float)(2 * tid + 1));
    float inv_c = __expf(-LN1000_OVER_512 * (float)(2 * tid));
    f32x4 acc = {0.f, 0.f, 0.f, 0.f};
    int m0 = (w & 1) * 16, n0 = (w >> 1) * 16;

    if (bid < 64) {
      // ---- v partial: ks selects both K-window and roi coordinate
      int ntb = bid & 15, ks = bid >> 4;
      int d0 = ntb * 32;
      for (int c = 0; c < 2; ++c) {
        int k0 = ks * 512 + c * 256;
        for (int j = 0; j < 32; ++j) {
          float z = rois[j * 5 + 1 + ks];
          float val = c ? __cosf(z * inv_c) : __sinf(z * inv_s);
          Al[j * 264 + tid] = f2bf(val);
        }
        #pragma unroll
        for (int jj = 0; jj < 8; ++jj) {
          int fid = tid + jj * 256;
          int dd = fid >> 6, k4 = fid & 63;
          float4 v = *(const float4*)(V_box + (size_t)(d0 + dd) * 2048 + k0 + k4 * 4);
          *(short4v*)(Bl + dd * 264 + k4 * 4) = f2bf4(v);
        }
        __syncthreads();
        const short* ap = Al + (m0 + m) * 264 + q * 8;
        const short* bp = Bl + (n0 + m) * 264 + q * 8;
        #pragma unroll
        for (int kk = 0; kk < 8; ++kk) {
          short8 a = *(const short8*)(ap + kk * 32);
          short8 b = *(const short8*)(bp + kk * 32);
          acc = __builtin_amdgcn_mfma_f32_16x16x32_bf16(a, b, acc, 0, 0, 0);
        }
        __syncthreads();
      }
      #pragma unroll
      for (int r = 0; r < 4; ++r)
        ws[PARTV_OFF + ks * 16384 + (m0 + q * 4 + r) * 512 + d0 + n0 + m] = acc[r];
    } else {
      // ---- img GEMM: rows 0..111 (pad to 128), cols 256
      int t = bid - 64;
      int mt = t >> 3, nt = t & 7;
      int rm0 = mt * 32, o0 = nt * 32;
      int khalf = mt >> 1;
      int posbase = rm0 - khalf * 64;
      for (int c = 0; c < 2; ++c) {
        int k0 = khalf * 512 + c * 256;
        for (int j = 0; j < 32; ++j) {
          float z = (float)(posbase + j);
          float val = c ? __cosf(z * inv_c) : __sinf(z * inv_s);
          Al[j * 264 + tid] = f2bf(val);
        }
        #pragma unroll
        for (int jj = 0; jj < 8; ++jj) {
          int fid = tid + jj * 256;
          int dd = fid >> 6, k4 = fid & 63;
          float4 v = *(const float4*)(W_im + (size_t)(o0 + dd) * 1024 + k0 + k4 * 4);
          *(short4v*)(Bl + dd * 264 + k4 * 4) = f2bf4(v);
        }
        __syncthreads();
        const short* ap = Al + (m0 + m) * 264 + q * 8;
        const short* bp = Bl + (n0 + m) * 264 + q * 8;
        #pragma unroll
        for (int kk = 0; kk < 8; ++kk) {
          short8 a = *(const short8*)(ap + kk * 32);
          short8 b = *(const short8*)(bp + kk * 32);
          acc = __builtin_amdgcn_mfma_f32_16x16x32_bf16(a, b, acc, 0, 0, 0);
        }
        __syncthreads();
      }
      short* imgb = (short*)(ws + IMGB_OFF);
      #pragma unroll
      for (int r = 0; r < 4; ++r) {
        int row = rm0 + m0 + q * 4 + r;
        if (row < 112) imgb[row * 256 + o0 + n0 + m] = f2bf(acc[r]);
      }
    }
  } else {
    // ---- app GEMM
    short* Al = sh;                  // [32 px][264 c]
    short* Bl = sh + 32 * 264;       // [64 k][264 c]
    int t = bid - 96;
    int b = t / 96, pt = t % 96;
    int p0 = pt * 32;
    const float* xb = x + (size_t)b * 786432;
    #pragma unroll
    for (int j = 0; j < 8; ++j) {
      int fid = tid + j * 256;
      int c = fid >> 3, pj = fid & 7;
      float4 v = *(const float4*)(xb + c * 3072 + p0 + pj * 4);
      Al[(pj * 4 + 0) * 264 + c] = f2bf(v.x);
      Al[(pj * 4 + 1) * 264 + c] = f2bf(v.y);
      Al[(pj * 4 + 2) * 264 + c] = f2bf(v.z);
      Al[(pj * 4 + 3) * 264 + c] = f2bf(v.w);
    }
    #pragma unroll
    for (int j = 0; j < 16; ++j) {
      int fid = tid + j * 256;
      int k = fid >> 6, c4 = fid & 63;
      short4v s4 = {0, 0, 0, 0};
      if (k < 49) s4 = f2bf4(*(const float4*)(conv_w + k * 256 + c4 * 4));
      *(short4v*)(Bl + k * 264 + c4 * 4) = s4;
    }
    __syncthreads();
    int n0 = w * 16;
    f32x4 acc0 = {0.f, 0.f, 0.f, 0.f}, acc1 = {0.f, 0.f, 0.f, 0.f};
    const short* ap = Al + m * 264 + q * 8;
    const short* bp = Bl + (n0 + m) * 264 + q * 8;
    #pragma unroll
    for (int kk = 0; kk < 8; ++kk) {
      short8 b8 = *(const short8*)(bp + kk * 32);
      short8 a0 = *(const short8*)(ap + kk * 32);
      short8 a1 = *(const short8*)(ap + 16 * 264 + kk * 32);
      acc0 = __builtin_amdgcn_mfma_f32_16x16x32_bf16(a0, b8, acc0, 0, 0, 0);
      acc1 = __builtin_amdgcn_mfma_f32_16x16x32_bf16(a1, b8, acc1, 0, 0, 0);
    }
    int k = n0 + m;
    if (k < 49) {
      float bias = conv_b[k];
      float* apt = ws + APPT_OFF + (size_t)b * 159744;
      #pragma unroll
      for (int r = 0; r < 4; ++r) {
        int p = p0 + q * 4 + r;
        apt[(size_t)p * 52 + k] = acc0[r] + bias;
        apt[(size_t)(p + 16) * 52 + k] = acc1[r] + bias;
      }
    }
  }
}

// K2: bvec_bf16[n][12544] = v(32x512).W_box(12544x512)^T
__global__ __launch_bounds__(256) void k2(const float* __restrict__ W_box,
                                          float* __restrict__ ws) {
  __shared__ __align__(16) short Av[32 * 520];
  __shared__ __align__(16) short Bl[32 * 520];
  int tid = threadIdx.x;
  int j0 = blockIdx.x * 32;   // 392 blocks
  #pragma unroll
  for (int j = 0; j < 16; ++j) {
    int fid = tid + j * 256;
    int n = fid >> 7, d4 = fid & 127;
    const float* p = ws + PARTV_OFF + n * 512 + d4 * 4;
    float4 v0 = *(const float4*)(p);
    float4 v1 = *(const float4*)(p + 16384);
    float4 v2 = *(const float4*)(p + 32768);
    float4 v3 = *(const float4*)(p + 49152);
    float4 s; s.x = v0.x + v1.x + v2.x + v3.x; s.y = v0.y + v1.y + v2.y + v3.y;
    s.z = v0.z + v1.z + v2.z + v3.z; s.w = v0.w + v1.w + v2.w + v3.w;
    *(short4v*)(Av + n * 520 + d4 * 4) = f2bf4(s);
  }
  #pragma unroll
  for (int j = 0; j < 16; ++j) {
    int fid = tid + j * 256;
    int rr = fid >> 7, d4 = fid & 127;
    float4 v = *(const float4*)(W_box + (size_t)(j0 + rr) * 512 + d4 * 4);
    *(short4v*)(Bl + rr * 520 + d4 * 4) = f2bf4(v);
  }
  __syncthreads();
  int w = tid >> 6, lane = tid & 63;
  int q = lane >> 4, m = lane & 15;
  int m0 = (w & 1) * 16, n0 = (w >> 1) * 16;
  f32x4 acc = {0.f, 0.f, 0.f, 0.f};
  const short* ap = Av + (m0 + m) * 520 + q * 8;
  const short* bp = Bl + (n0 + m) * 520 + q * 8;
  #pragma unroll
  for (int kk = 0; kk < 16; ++kk) {
    short8 a = *(const short8*)(ap + kk * 32);
    short8 b = *(const short8*)(bp + kk * 32);
    acc = __builtin_amdgcn_mfma_f32_16x16x32_bf16(a, b, acc, 0, 0, 0);
  }
  short* bvb = (short*)(ws + BVB_OFF);
  #pragma unroll
  for (int r = 0; r < 4; ++r) {
    int row = m0 + q * 4 + r;
    int col = j0 + n0 + m;
    bvb[(size_t)row * 12544 + col] = f2bf(acc[r]);
  }
}

// K3: gx[1568][64] = bvec.imgx^T ; gy[1568][48] = bvec.imgy^T  (98 blocks)
__global__ __launch_bounds__(256) void k3(float* __restrict__ ws) {
  __shared__ __align__(16) short Al[32 * 264];
  int tid = threadIdx.x;
  int half = blockIdx.x & 1, rb = blockIdx.x >> 1;
  int r0 = rb * 32;
  const short* bvb = (const short*)(ws + BVB_OFF);
  #pragma unroll
  for (int j = 0; j < 4; ++j) {
    int fid = tid + j * 256;
    int rr = fid >> 5, o8 = fid & 31;
    *(short8*)(Al + rr * 264 + o8 * 8) = *(const short8*)(bvb + (size_t)(r0 + rr) * 256 + o8 * 8);
  }
  __syncthreads();
  int w = tid >> 6, lane = tid & 63;
  int q = lane >> 4, m = lane & 15;
  int nct = half ? 3 : 4;
  if (w < nct) {
    const short* imgb = (const short*)(ws + IMGB_OFF) + (half ? 64 * 256 : 0);
    int ct = w;
    f32x4 acc0 = {0.f, 0.f, 0.f, 0.f}, acc1 = {0.f, 0.f, 0.f, 0.f};
    const short* ap0 = Al + m * 264 + q * 8;
    const short* ap1 = Al + (16 + m) * 264 + q * 8;
    const short* bp  = imgb + (ct * 16 + m) * 256 + q * 8;
    #pragma unroll
    for (int kk = 0; kk < 8; ++kk) {
      short8 b8 = *(const short8*)(bp + kk * 32);
      short8 a0 = *(const short8*)(ap0 + kk * 32);
      short8 a1 = *(const short8*)(ap1 + kk * 32);
      acc0 = __builtin_amdgcn_mfma_f32_16x16x32_bf16(a0, b8, acc0, 0, 0, 0);
      acc1 = __builtin_amdgcn_mfma_f32_16x16x32_bf16(a1, b8, acc1, 0, 0, 0);
    }
    float* outp = ws + (half ? GY_OFF : GX_OFF);
    int stride = half ? 48 : 64;
    int col = ct * 16 + m;
    #pragma unroll
    for (int r = 0; r < 4; ++r) {
      outp[(r0 + q * 4 + r) * stride + col]      = acc0[r];
      outp[(r0 + 16 + q * 4 + r) * stride + col] = acc1[r];
    }
  }
}

// K4: one (n,b,tile) per block, 1 pixel/thread. logits -> softmax -> ordered write.
__global__ __launch_bounds__(256) void k4(const float* __restrict__ rois,
                                          const float* __restrict__ ws,
                                          float* __restrict__ out) {
  __shared__ float gyl[2352];    // [49][48]
  __shared__ float gxs[392];     // [49][8] h-slice
  __shared__ int rank_sh;
  int tid = threadIdx.x, bid = blockIdx.x;   // 1536 = n*48 + b*12 + tile
  int n = bid / 48;
  int rem = bid % 48;
  int b = rem / 12, tile = rem % 12;
  int h0 = (tile * 256) / 48;
  #pragma unroll
  for (int j = 0; j < 3; ++j) {
    int id = tid + j * 256;
    if (id < 588) *(float4*)(gyl + id * 4) = *(const float4*)(ws + GY_OFF + n * 2352 + id * 4);
  }
  #pragma unroll
  for (int j = 0; j < 2; ++j) {
    int id = tid + j * 256;
    if (id < 392) {
      int row = id >> 3, c = id & 7;
      int col = h0 + c; if (col > 63) col = 63;
      gxs[id] = ws[GX_OFF + (n * 49 + row) * 64 + col];
    }
  }
  if (tid == 0) {
    float my = rois[n * 5];
    int r = 0;
    for (int mm = 0; mm < 32; ++mm) {
      float vm = rois[mm * 5];
      if (vm < my || (vm == my && mm < n)) ++r;
    }
    rank_sh = r;
  }
  __syncthreads();
  int pix = tile * 256 + tid;
  int h = pix / 48, wv = pix - h * 48;
  int dh = h - h0;
  float lg[49];
  const float* ap = ws + APPT_OFF + (size_t)(b * 3072 + pix) * 52;
  #pragma unroll
  for (int qq = 0; qq < 12; ++qq) {
    float4 tv = *(const float4*)(ap + qq * 4);
    lg[qq * 4 + 0] = tv.x; lg[qq * 4 + 1] = tv.y; lg[qq * 4 + 2] = tv.z; lg[qq * 4 + 3] = tv.w;
  }
  lg[48] = ap[48];
  #pragma unroll
  for (int k = 0; k < 49; ++k)
    lg[k] += gxs[k * 8 + dh] + gyl[k * 48 + wv];
  float mx = lg[0];
  #pragma unroll
  for (int k = 1; k < 49; ++k) mx = fmaxf(mx, lg[k]);
  float s = 0.f;
  #pragma unroll
  for (int k = 0; k < 49; ++k) { float e = __expf(lg[k] - mx); lg[k] = e; s += e; }
  float inv = 1.f / s;
  float* op = out + (size_t)(rank_sh * 4 + b) * 150528 + pix;
  #pragma unroll
  for (int k = 0; k < 49; ++k)
    op[(size_t)k * 3072] = lg[k] * inv;
}

extern "C" void kernel_launch(void* const* d_in, const int* in_sizes, int n_in,
                              void* d_out, int out_size, void* d_ws, size_t ws_size,
                              hipStream_t stream) {
  const float* x      = (const float*)d_in[0];
  const float* rois   = (const float*)d_in[1];
  const float* V_box  = (const float*)d_in[2];
  const float* W_box  = (const float*)d_in[3];
  const float* W_im   = (const float*)d_in[4];
  const float* conv_w = (const float*)d_in[5];
  const float* conv_b = (const float*)d_in[6];
  float* ws  = (float*)d_ws;
  float* out = (float*)d_out;

  hipLaunchKernelGGL(k1, dim3(480),  dim3(256), 0, stream, rois, W_im, V_box, x, conv_w, conv_b, ws);
  hipLaunchKernelGGL(k2, dim3(392),  dim3(256), 0, stream, W_box, ws);
  hipLaunchKernelGGL(k3, dim3(98),   dim3(256), 0, stream, ws);
  hipLaunchKernelGGL(k4, dim3(1536), dim3(256), 0, stream, rois, ws, out);
}